// Round 1
// baseline (498.873 us; speedup 1.0000x reference)
//
#include <hip/hip_runtime.h>
#include <hip/hip_bf16.h>
#include <cstdint>

#define TOKENS 8192
#define IN_F   4096
#define OUT_F  4096

#define BM 128
#define BN 128
#define BK 64

typedef __attribute__((ext_vector_type(8))) short bf16x8;
typedef __attribute__((ext_vector_type(4))) float f32x4;

#define GLOBAL_AS __attribute__((address_space(1)))
#define LDS_AS    __attribute__((address_space(3)))

__device__ __forceinline__ unsigned short f2bf(float f) {
  union { float f; unsigned int u; } v;
  v.f = f;
  unsigned int r = 0x7FFFu + ((v.u >> 16) & 1u);
  return (unsigned short)((v.u + r) >> 16);
}

__device__ __forceinline__ float softplus_f(float x) {
  return log1pf(expf(x));
}

// ---------------- prep kernels ----------------

__global__ void convert_x_kernel(const float* __restrict__ x,
                                 unsigned short* __restrict__ xb,
                                 long long n4) {
  long long i = (long long)blockIdx.x * blockDim.x + threadIdx.x;
  long long stride = (long long)gridDim.x * blockDim.x;
  for (; i < n4; i += stride) {
    float4 m = reinterpret_cast<const float4*>(x)[i];
    ushort4 o;
    o.x = f2bf(m.x); o.y = f2bf(m.y); o.z = f2bf(m.z); o.w = f2bf(m.w);
    reinterpret_cast<ushort4*>(xb)[i] = o;
  }
}

__global__ void sample_weight_kernel(const float* __restrict__ mu,
                                     const float* __restrict__ rho,
                                     const float* __restrict__ eps,
                                     unsigned short* __restrict__ wb,
                                     long long n4) {
  long long i = (long long)blockIdx.x * blockDim.x + threadIdx.x;
  long long stride = (long long)gridDim.x * blockDim.x;
  for (; i < n4; i += stride) {
    float4 m = reinterpret_cast<const float4*>(mu)[i];
    float4 r = reinterpret_cast<const float4*>(rho)[i];
    float4 e = reinterpret_cast<const float4*>(eps)[i];
    ushort4 o;
    o.x = f2bf(fmaf(softplus_f(r.x), e.x, m.x));
    o.y = f2bf(fmaf(softplus_f(r.y), e.y, m.y));
    o.z = f2bf(fmaf(softplus_f(r.z), e.z, m.z));
    o.w = f2bf(fmaf(softplus_f(r.w), e.w, m.w));
    reinterpret_cast<ushort4*>(wb)[i] = o;
  }
}

__global__ void bias_kernel(const float* __restrict__ mu,
                            const float* __restrict__ rho,
                            const float* __restrict__ eps,
                            float* __restrict__ b) {
  int i = blockIdx.x * blockDim.x + threadIdx.x;
  if (i < OUT_F) b[i] = fmaf(softplus_f(rho[i]), eps[i], mu[i]);
}

// ---------------- GEMM: C[t][o] = sum_k Xb[t][k]*Wb[o][k] + bias[o] ----------------
// m97-style structure: 128x128 tile, BK=64, 4 waves (each 64x64 = 4x4 frags of 16x16),
// global_load_lds width-16 staging, mfma_f32_16x16x32_bf16.

__global__ __launch_bounds__(256) void gemm_bt_kernel(
    const unsigned short* __restrict__ A,   // [TOKENS][IN_F] bf16
    const unsigned short* __restrict__ B,   // [OUT_F][IN_F] bf16
    const float* __restrict__ bias,         // [OUT_F]
    float* __restrict__ C)                  // [TOKENS][OUT_F]
{
  __shared__ unsigned short As[BM * BK];
  __shared__ unsigned short Bs[BN * BK];

  const int tid  = threadIdx.x;
  const int lane = tid & 63;
  const int wave = tid >> 6;   // 0..3
  const int wr   = wave >> 1;  // 0..1
  const int wc   = wave & 1;   // 0..1

  const int nTilesN = OUT_F / BN;   // 32
  const int bm = blockIdx.x / nTilesN;
  const int bn = blockIdx.x % nTilesN;

  const int row8 = lane >> 3;        // 0..7
  const int col8 = (lane & 7) * 8;   // 0..56 step 8

  f32x4 acc[4][4] = {};

  const unsigned short* aBase = A + (size_t)(bm * BM) * IN_F;
  const unsigned short* bBase = B + (size_t)(bn * BN) * IN_F;

  for (int k0 = 0; k0 < IN_F; k0 += BK) {
    // stage A tile: 16 chunks of 8 rows; wave w owns chunks w*4..w*4+3
#pragma unroll
    for (int c = 0; c < 4; ++c) {
      int chunk = wave * 4 + c;
      int row = chunk * 8 + row8;
      const unsigned short* g = aBase + (size_t)row * IN_F + k0 + col8;
      __builtin_amdgcn_global_load_lds((const GLOBAL_AS void*)g,
                                       (LDS_AS void*)&As[chunk * 512],
                                       16, 0, 0);
    }
#pragma unroll
    for (int c = 0; c < 4; ++c) {
      int chunk = wave * 4 + c;
      int row = chunk * 8 + row8;
      const unsigned short* g = bBase + (size_t)row * IN_F + k0 + col8;
      __builtin_amdgcn_global_load_lds((const GLOBAL_AS void*)g,
                                       (LDS_AS void*)&Bs[chunk * 512],
                                       16, 0, 0);
    }
    __syncthreads();  // compiler drains vmcnt before s_barrier

#pragma unroll
    for (int kk = 0; kk < 2; ++kk) {
      bf16x8 a[4], b[4];
#pragma unroll
      for (int mi = 0; mi < 4; ++mi) {
        int r = wr * 64 + mi * 16 + (lane & 15);
        a[mi] = *reinterpret_cast<const bf16x8*>(&As[r * BK + kk * 32 + (lane >> 4) * 8]);
      }
#pragma unroll
      for (int ni = 0; ni < 4; ++ni) {
        int r = wc * 64 + ni * 16 + (lane & 15);
        b[ni] = *reinterpret_cast<const bf16x8*>(&Bs[r * BK + kk * 32 + (lane >> 4) * 8]);
      }
#pragma unroll
      for (int mi = 0; mi < 4; ++mi)
#pragma unroll
        for (int ni = 0; ni < 4; ++ni)
          acc[mi][ni] = __builtin_amdgcn_mfma_f32_16x16x32_bf16(a[mi], b[ni], acc[mi][ni], 0, 0, 0);
    }
    __syncthreads();
  }

  // epilogue: C/D layout col=lane&15, row=(lane>>4)*4+reg  [m89-verified]
#pragma unroll
  for (int ni = 0; ni < 4; ++ni) {
    int colg = bn * BN + wc * 64 + ni * 16 + (lane & 15);
    float bv = bias[colg];
#pragma unroll
    for (int mi = 0; mi < 4; ++mi) {
      int rowg = bm * BM + wr * 64 + mi * 16 + (lane >> 4) * 4;
#pragma unroll
      for (int r = 0; r < 4; ++r) {
        C[(size_t)(rowg + r) * OUT_F + colg] = acc[mi][ni][r] + bv;
      }
    }
  }
}

// ---------------- fallback (only if ws too small) ----------------

__global__ void fallback_kernel(const float* __restrict__ x,
                                const float* __restrict__ wmu,
                                const float* __restrict__ wrho,
                                const float* __restrict__ weps,
                                const float* __restrict__ bmu,
                                const float* __restrict__ brho,
                                const float* __restrict__ beps,
                                float* __restrict__ out) {
  int o = blockIdx.x * blockDim.x + threadIdx.x;
  int t = blockIdx.y;
  float s = 0.f;
  const float* xr = x + (size_t)t * IN_F;
  const float* wm = wmu + (size_t)o * IN_F;
  const float* wr = wrho + (size_t)o * IN_F;
  const float* we = weps + (size_t)o * IN_F;
  for (int k = 0; k < IN_F; ++k)
    s += xr[k] * fmaf(softplus_f(wr[k]), we[k], wm[k]);
  out[(size_t)t * OUT_F + o] = s + fmaf(softplus_f(brho[o]), beps[o], bmu[o]);
}

// ---------------- launch ----------------

extern "C" void kernel_launch(void* const* d_in, const int* in_sizes, int n_in,
                              void* d_out, int out_size, void* d_ws, size_t ws_size,
                              hipStream_t stream) {
  const float* x    = (const float*)d_in[0];
  const float* wmu  = (const float*)d_in[1];
  const float* wrho = (const float*)d_in[2];
  const float* bmu  = (const float*)d_in[3];
  const float* brho = (const float*)d_in[4];
  const float* weps = (const float*)d_in[5];
  const float* beps = (const float*)d_in[6];
  float* out = (float*)d_out;

  const size_t xb_off   = 0;
  const size_t wb_off   = (size_t)TOKENS * IN_F * 2;            // 64 MB
  const size_t bias_off = wb_off + (size_t)OUT_F * IN_F * 2;    // +32 MB
  const size_t needed   = bias_off + (size_t)OUT_F * 4;

  if (ws_size < needed) {
    dim3 g(OUT_F / 256, TOKENS);
    hipLaunchKernelGGL(fallback_kernel, g, dim3(256), 0, stream,
                       x, wmu, wrho, weps, bmu, brho, beps, out);
    return;
  }

  unsigned short* xb = (unsigned short*)((char*)d_ws + xb_off);
  unsigned short* wb = (unsigned short*)((char*)d_ws + wb_off);
  float* bias = (float*)((char*)d_ws + bias_off);

  hipLaunchKernelGGL(convert_x_kernel, dim3(2048), dim3(256), 0, stream,
                     x, xb, (long long)TOKENS * IN_F / 4);
  hipLaunchKernelGGL(sample_weight_kernel, dim3(2048), dim3(256), 0, stream,
                     wmu, wrho, weps, wb, (long long)OUT_F * IN_F / 4);
  hipLaunchKernelGGL(bias_kernel, dim3(16), dim3(256), 0, stream,
                     bmu, brho, beps, bias);

  hipLaunchKernelGGL(gemm_bt_kernel, dim3((TOKENS / BM) * (OUT_F / BN)), dim3(256), 0, stream,
                     xb, wb, bias, out);
}

// Round 2
// 367.097 us; speedup vs baseline: 1.3590x; 1.3590x over previous
//
#include <hip/hip_runtime.h>
#include <hip/hip_bf16.h>
#include <cstdint>

#define TOKENS 8192
#define IN_F   4096
#define OUT_F  4096

#define BM 256
#define BN 256
#define BK 32
#define NT (IN_F / BK)   // 128 K-tiles
#define THREADS 512

typedef __attribute__((ext_vector_type(8))) short bf16x8;
typedef __attribute__((ext_vector_type(4))) float f32x4;

#define GLOBAL_AS __attribute__((address_space(1)))
#define LDS_AS    __attribute__((address_space(3)))

// raw barrier: no vmcnt drain (unlike __syncthreads); memory clobber stops
// the compiler from moving LDS/global ops across it
#define BARRIER() do { __builtin_amdgcn_s_barrier(); asm volatile("" ::: "memory"); } while (0)
#define VMCNT(n)  do { asm volatile("s_waitcnt vmcnt(" #n ")" ::: "memory"); } while (0)

__device__ __forceinline__ unsigned short f2bf(float f) {
  union { float f; unsigned int u; } v;
  v.f = f;
  unsigned int r = 0x7FFFu + ((v.u >> 16) & 1u);
  return (unsigned short)((v.u + r) >> 16);
}

__device__ __forceinline__ float softplus_f(float x) {
  return log1pf(expf(x));
}

// ---------------- prep kernels ----------------

__global__ void convert_x_kernel(const float* __restrict__ x,
                                 unsigned short* __restrict__ xb,
                                 long long n4) {
  long long i = (long long)blockIdx.x * blockDim.x + threadIdx.x;
  long long stride = (long long)gridDim.x * blockDim.x;
  for (; i < n4; i += stride) {
    float4 m = reinterpret_cast<const float4*>(x)[i];
    ushort4 o;
    o.x = f2bf(m.x); o.y = f2bf(m.y); o.z = f2bf(m.z); o.w = f2bf(m.w);
    reinterpret_cast<ushort4*>(xb)[i] = o;
  }
}

__global__ void sample_weight_kernel(const float* __restrict__ mu,
                                     const float* __restrict__ rho,
                                     const float* __restrict__ eps,
                                     unsigned short* __restrict__ wb,
                                     long long n4) {
  long long i = (long long)blockIdx.x * blockDim.x + threadIdx.x;
  long long stride = (long long)gridDim.x * blockDim.x;
  for (; i < n4; i += stride) {
    float4 m = reinterpret_cast<const float4*>(mu)[i];
    float4 r = reinterpret_cast<const float4*>(rho)[i];
    float4 e = reinterpret_cast<const float4*>(eps)[i];
    ushort4 o;
    o.x = f2bf(fmaf(softplus_f(r.x), e.x, m.x));
    o.y = f2bf(fmaf(softplus_f(r.y), e.y, m.y));
    o.z = f2bf(fmaf(softplus_f(r.z), e.z, m.z));
    o.w = f2bf(fmaf(softplus_f(r.w), e.w, m.w));
    reinterpret_cast<ushort4*>(wb)[i] = o;
  }
}

__global__ void bias_kernel(const float* __restrict__ mu,
                            const float* __restrict__ rho,
                            const float* __restrict__ eps,
                            float* __restrict__ b) {
  int i = blockIdx.x * blockDim.x + threadIdx.x;
  if (i < OUT_F) b[i] = fmaf(softplus_f(rho[i]), eps[i], mu[i]);
}

// ---------------- GEMM: C[t][o] = sum_k Xb[t][k]*Wb[o][k] + bias[o] ----------------
// 256x256 tile, BK=32, 8 waves (2M x 4N), 4-slot LDS ring (128 KiB),
// 3-tile-deep global_load_lds pipeline with counted vmcnt, 2 phases/tile,
// setprio around MFMA clusters, conflict-free XOR-swizzled LDS.
//
// Swizzle (involution on 16B chunk index within a 64B row):
//   chunk' = chunk ^ (r&3) ^ ((r>>2)&1)
// applied on the per-lane GLOBAL source during staging (LDS dest stays linear,
// as global_load_lds requires) and on the ds_read address. Spreads 8
// consecutive rows over all 8 chunk slots -> 2 lanes/bank (free).

__global__ __launch_bounds__(THREADS, 2) void gemm_bt_kernel(
    const unsigned short* __restrict__ A,   // [TOKENS][IN_F] bf16
    const unsigned short* __restrict__ B,   // [OUT_F][IN_F] bf16
    const float* __restrict__ bias,         // [OUT_F]
    float* __restrict__ C)                  // [TOKENS][OUT_F]
{
  // 4 slots x (A: 256x32 + B: 256x32) bf16 = 4 x 32 KiB = 128 KiB
  __shared__ unsigned short lds[4 * 16384];

  const int tid  = threadIdx.x;
  const int lane = tid & 63;
  const int wave = tid >> 6;      // 0..7
  const int wm   = wave >> 2;     // 0..1  (M half: 128 rows)
  const int wn   = wave & 3;      // 0..3  (N quarter: 64 cols)

  // XCD-aware bijective swizzle: 512 blocks = 8 XCD chunks x 64; each chunk
  // is an 8x8 tile-square (chunk-grid 4 rows x 2 cols over 32x16 tiles)
  const int bid = blockIdx.x;
  const int wg  = (bid & 7) * 64 + (bid >> 3);
  const int ch  = wg >> 6;        // 0..7
  const int idx = wg & 63;
  const int bm  = (ch >> 1) * 8 + (idx >> 3);  // 0..31
  const int bn  = (ch & 1) * 8 + (idx & 7);    // 0..15

  const int lane15 = lane & 15;
  // ds_read chunk offset (elements): (cgrp ^ mix(r)) * 8, mix lane-invariant per frag set
  const int rdoff = (((lane >> 4) ^ ((lane & 3) ^ ((lane >> 2) & 1))) << 3);
  // staging: per-lane pre-swizzled global source column (elements)
  const int scol  = (((lane & 3) ^ (((lane >> 2) & 3) ^ ((lane >> 4) & 1))) << 3);
  const int srow  = lane >> 2;    // 0..15 (row within 16-row wave-load)

  const unsigned short* Ag = A + (size_t)(bm * BM) * IN_F;
  const unsigned short* Bg = B + (size_t)(bn * BN) * IN_F;
  // per-thread staging bases: row = wave*32 + i*16 + srow, col = k0 + scol
  const unsigned short* AgT = Ag + (size_t)(wave * 32 + srow) * IN_F + scol;
  const unsigned short* BgT = Bg + (size_t)(wave * 32 + srow) * IN_F + scol;

  f32x4 acc[8][4] = {};

  auto stageA = [&](int t) {
    unsigned short* dst = &lds[(t & 3) * 16384 + wave * 1024];
    const int k0 = t * BK;
#pragma unroll
    for (int i = 0; i < 2; ++i) {
      const unsigned short* g = AgT + (size_t)i * 16 * IN_F + k0;
      __builtin_amdgcn_global_load_lds((const GLOBAL_AS void*)g,
                                       (LDS_AS void*)(dst + i * 512), 16, 0, 0);
    }
  };
  auto stageB = [&](int t) {
    unsigned short* dst = &lds[(t & 3) * 16384 + 8192 + wave * 1024];
    const int k0 = t * BK;
#pragma unroll
    for (int i = 0; i < 2; ++i) {
      const unsigned short* g = BgT + (size_t)i * 16 * IN_F + k0;
      __builtin_amdgcn_global_load_lds((const GLOBAL_AS void*)g,
                                       (LDS_AS void*)(dst + i * 512), 16, 0, 0);
    }
  };

  // prologue: fill 3 pipeline stages (12 loads/thread), wait for tile 0 only
  stageA(0); stageB(0);
  stageA(1); stageB(1);
  stageA(2); stageB(2);
  VMCNT(8);
  BARRIER();

  for (int t = 0; t < NT; ++t) {
    const unsigned short* As = &lds[(t & 3) * 16384];
    const unsigned short* Bs = As + 8192;

    // ---- phase 0: rows [wm*128, +64) x all 64 cols ----
    bf16x8 av[4], bv[4];
#pragma unroll
    for (int mi = 0; mi < 4; ++mi)
      av[mi] = *reinterpret_cast<const bf16x8*>(As + (wm * 128 + mi * 16 + lane15) * 32 + rdoff);
#pragma unroll
    for (int ni = 0; ni < 4; ++ni)
      bv[ni] = *reinterpret_cast<const bf16x8*>(Bs + (wn * 64 + ni * 16 + lane15) * 32 + rdoff);
    if (t + 3 < NT) stageA(t + 3);
    BARRIER();
    __builtin_amdgcn_s_setprio(1);
#pragma unroll
    for (int mi = 0; mi < 4; ++mi)
#pragma unroll
      for (int ni = 0; ni < 4; ++ni)
        acc[mi][ni] = __builtin_amdgcn_mfma_f32_16x16x32_bf16(av[mi], bv[ni], acc[mi][ni], 0, 0, 0);
    __builtin_amdgcn_s_setprio(0);
    BARRIER();

    // ---- phase 1: rows [wm*128+64, +64) x all 64 cols (reuse bv) ----
    bf16x8 av2[4];
#pragma unroll
    for (int mi = 0; mi < 4; ++mi)
      av2[mi] = *reinterpret_cast<const bf16x8*>(As + (wm * 128 + 64 + mi * 16 + lane15) * 32 + rdoff);
    if (t + 3 < NT) stageB(t + 3);
    BARRIER();
    __builtin_amdgcn_s_setprio(1);
#pragma unroll
    for (int mi = 0; mi < 4; ++mi)
#pragma unroll
      for (int ni = 0; ni < 4; ++ni)
        acc[4 + mi][ni] = __builtin_amdgcn_mfma_f32_16x16x32_bf16(av2[mi], bv[ni], acc[4 + mi][ni], 0, 0, 0);
    __builtin_amdgcn_s_setprio(0);
    // tile boundary: guarantee tile t+1 landed; tiles t+2,t+3 stay in flight
    if (t < NT - 3)       { VMCNT(8); }
    else if (t == NT - 3) { VMCNT(4); }
    else                  { VMCNT(0); }   // only stale loads remain; free
    BARRIER();
  }

  // epilogue: C/D layout col=lane&15, row=(lane>>4)*4+reg
  const int colg0 = bn * BN + wn * 64 + lane15;
  const int rowg0 = bm * BM + wm * 128 + (lane >> 4) * 4;
#pragma unroll
  for (int ni = 0; ni < 4; ++ni) {
    const int colg = colg0 + ni * 16;
    const float bvs = bias[colg];
#pragma unroll
    for (int mi = 0; mi < 8; ++mi) {
      const int rowg = rowg0 + mi * 16;
#pragma unroll
      for (int r = 0; r < 4; ++r)
        C[(size_t)(rowg + r) * OUT_F + colg] = acc[mi][ni][r] + bvs;
    }
  }
}

// ---------------- fallback (only if ws too small) ----------------

__global__ void fallback_kernel(const float* __restrict__ x,
                                const float* __restrict__ wmu,
                                const float* __restrict__ wrho,
                                const float* __restrict__ weps,
                                const float* __restrict__ bmu,
                                const float* __restrict__ brho,
                                const float* __restrict__ beps,
                                float* __restrict__ out) {
  int o = blockIdx.x * blockDim.x + threadIdx.x;
  int t = blockIdx.y;
  float s = 0.f;
  const float* xr = x + (size_t)t * IN_F;
  const float* wm = wmu + (size_t)o * IN_F;
  const float* wr = wrho + (size_t)o * IN_F;
  const float* we = weps + (size_t)o * IN_F;
  for (int k = 0; k < IN_F; ++k)
    s += xr[k] * fmaf(softplus_f(wr[k]), we[k], wm[k]);
  out[(size_t)t * OUT_F + o] = s + fmaf(softplus_f(brho[o]), beps[o], bmu[o]);
}

// ---------------- launch ----------------

extern "C" void kernel_launch(void* const* d_in, const int* in_sizes, int n_in,
                              void* d_out, int out_size, void* d_ws, size_t ws_size,
                              hipStream_t stream) {
  const float* x    = (const float*)d_in[0];
  const float* wmu  = (const float*)d_in[1];
  const float* wrho = (const float*)d_in[2];
  const float* bmu  = (const float*)d_in[3];
  const float* brho = (const float*)d_in[4];
  const float* weps = (const float*)d_in[5];
  const float* beps = (const float*)d_in[6];
  float* out = (float*)d_out;

  const size_t xb_off   = 0;
  const size_t wb_off   = (size_t)TOKENS * IN_F * 2;            // 64 MB
  const size_t bias_off = wb_off + (size_t)OUT_F * IN_F * 2;    // +32 MB
  const size_t needed   = bias_off + (size_t)OUT_F * 4;

  if (ws_size < needed) {
    dim3 g(OUT_F / 256, TOKENS);
    hipLaunchKernelGGL(fallback_kernel, g, dim3(256), 0, stream,
                       x, wmu, wrho, weps, bmu, brho, beps, out);
    return;
  }

  unsigned short* xb = (unsigned short*)((char*)d_ws + xb_off);
  unsigned short* wb = (unsigned short*)((char*)d_ws + wb_off);
  float* bias = (float*)((char*)d_ws + bias_off);

  hipLaunchKernelGGL(convert_x_kernel, dim3(2048), dim3(256), 0, stream,
                     x, xb, (long long)TOKENS * IN_F / 4);
  hipLaunchKernelGGL(sample_weight_kernel, dim3(2048), dim3(256), 0, stream,
                     wmu, wrho, weps, wb, (long long)OUT_F * IN_F / 4);
  hipLaunchKernelGGL(bias_kernel, dim3(16), dim3(256), 0, stream,
                     bmu, brho, beps, bias);

  hipLaunchKernelGGL(gemm_bt_kernel,
                     dim3((TOKENS / BM) * (OUT_F / BN)), dim3(THREADS), 0, stream,
                     xb, wb, bias, out);
}

// Round 3
// 330.692 us; speedup vs baseline: 1.5086x; 1.1101x over previous
//
#include <hip/hip_runtime.h>
#include <hip/hip_bf16.h>
#include <cstdint>

#define TOKENS 8192
#define IN_F   4096
#define OUT_F  4096

#define BM 256
#define BN 256
#define BK 64
#define NT (IN_F / BK)   // 64 K-tiles
#define THREADS 512

typedef __attribute__((ext_vector_type(8))) short bf16x8;
typedef __attribute__((ext_vector_type(4))) float f32x4;

#define GLOBAL_AS __attribute__((address_space(1)))
#define LDS_AS    __attribute__((address_space(3)))

#define BARRIER() do { __builtin_amdgcn_s_barrier(); asm volatile("" ::: "memory"); } while (0)
#define VMCNT(n)  do { asm volatile("s_waitcnt vmcnt(" #n ")" ::: "memory"); } while (0)

__device__ __forceinline__ unsigned short f2bf(float f) {
  union { float f; unsigned int u; } v;
  v.f = f;
  unsigned int r = 0x7FFFu + ((v.u >> 16) & 1u);
  return (unsigned short)((v.u + r) >> 16);
}

__device__ __forceinline__ float softplus_f(float x) {
  return log1pf(expf(x));
}

// ---------------- prep kernels ----------------

__global__ void convert_x_kernel(const float* __restrict__ x,
                                 unsigned short* __restrict__ xb,
                                 long long n4) {
  long long i = (long long)blockIdx.x * blockDim.x + threadIdx.x;
  long long stride = (long long)gridDim.x * blockDim.x;
  for (; i < n4; i += stride) {
    float4 m = reinterpret_cast<const float4*>(x)[i];
    ushort4 o;
    o.x = f2bf(m.x); o.y = f2bf(m.y); o.z = f2bf(m.z); o.w = f2bf(m.w);
    reinterpret_cast<ushort4*>(xb)[i] = o;
  }
}

__global__ void sample_weight_kernel(const float* __restrict__ mu,
                                     const float* __restrict__ rho,
                                     const float* __restrict__ eps,
                                     unsigned short* __restrict__ wb,
                                     long long n4) {
  long long i = (long long)blockIdx.x * blockDim.x + threadIdx.x;
  long long stride = (long long)gridDim.x * blockDim.x;
  for (; i < n4; i += stride) {
    float4 m = reinterpret_cast<const float4*>(mu)[i];
    float4 r = reinterpret_cast<const float4*>(rho)[i];
    float4 e = reinterpret_cast<const float4*>(eps)[i];
    ushort4 o;
    o.x = f2bf(fmaf(softplus_f(r.x), e.x, m.x));
    o.y = f2bf(fmaf(softplus_f(r.y), e.y, m.y));
    o.z = f2bf(fmaf(softplus_f(r.z), e.z, m.z));
    o.w = f2bf(fmaf(softplus_f(r.w), e.w, m.w));
    reinterpret_cast<ushort4*>(wb)[i] = o;
  }
}

__global__ void bias_kernel(const float* __restrict__ mu,
                            const float* __restrict__ rho,
                            const float* __restrict__ eps,
                            float* __restrict__ b) {
  int i = blockIdx.x * blockDim.x + threadIdx.x;
  if (i < OUT_F) b[i] = fmaf(softplus_f(rho[i]), eps[i], mu[i]);
}

// ---------------- GEMM: 256x256 8-phase template (m201 port) ----------------
// 2 LDS slots x {A[256][64], B[256][64]} bf16 = 128 KiB. 8 waves (2M x 4N),
// per-wave out 128x64. Per K-tile: 4 quadrant phases x 16 MFMA; B-frags read
// once (phase q0) and held in regs. Half-tile staging skewed so vmcnt(4) at
// phases 4/8 guarantees the next tile while 2 stages stay in flight.
// LDS swizzle: chunk ^= (row & 7)  (16B chunks, 128B rows) — conflict-free;
// applied via pre-swizzled GLOBAL source (linear global_load_lds dest) and
// the matching XOR on ds_read addresses (rule 21 involution).

__global__ __launch_bounds__(THREADS, 2) void gemm_bt_kernel(
    const unsigned short* __restrict__ A,   // [TOKENS][IN_F] bf16
    const unsigned short* __restrict__ B,   // [OUT_F][IN_F] bf16
    const float* __restrict__ bias,         // [OUT_F]
    float* __restrict__ C)                  // [TOKENS][OUT_F]
{
  __shared__ unsigned short lds[2 * 32768]; // slot: A @ +0 (16384), B @ +16384

  const int tid  = threadIdx.x;
  const int lane = tid & 63;
  const int wave = tid >> 6;   // 0..7
  const int wm   = wave >> 2;  // 0..1
  const int wn   = wave & 3;   // 0..3

  // XCD-aware bijective block swizzle (512 = 8 XCD chunks x 64)
  const int bid = blockIdx.x;
  const int wg  = (bid & 7) * 64 + (bid >> 3);
  const int ch  = wg >> 6;
  const int idx = wg & 63;
  const int bm  = (ch >> 1) * 8 + (idx >> 3);  // 0..31
  const int bn  = (ch & 1) * 8 + (idx & 7);    // 0..15

  const int lane15 = lane & 15;
  const int cgrp   = lane >> 4;                // 0..3
  // ds_read element offsets (row = base + lane15, data-chunk = kk*4+cgrp,
  // lds-chunk = data-chunk ^ (row&7) = ^ (lane&7))
  const int rdoff0 = lane15 * 64 + ((cgrp ^ (lane & 7)) * 8);
  const int rdoff1 = lane15 * 64 + (((4 + cgrp) ^ (lane & 7)) * 8);

  // staging: per-lane pre-swizzled global source
  const int srow = lane >> 3;                  // 0..7
  const int scol = ((lane & 7) ^ srow) * 8;    // swizzled 16B chunk -> elems
  const unsigned short* Asrc = A + (size_t)(bm * BM + wave * 16 + srow) * IN_F + scol;
  const unsigned short* Bsrc = B + (size_t)(bn * BN + wave * 16 + srow) * IN_F + scol;

  f32x4 acc[8][4] = {};
  bf16x8 bv[4][2];

  auto stA = [&](int slot, int half, int t) {
    unsigned short* dst = &lds[slot * 32768 + half * 8192 + wave * 1024];
    const unsigned short* g = Asrc + (size_t)(half * 128) * IN_F + t * BK;
    __builtin_amdgcn_global_load_lds((const GLOBAL_AS void*)g,
                                     (LDS_AS void*)dst, 16, 0, 0);
    __builtin_amdgcn_global_load_lds((const GLOBAL_AS void*)(g + (size_t)8 * IN_F),
                                     (LDS_AS void*)(dst + 512), 16, 0, 0);
  };
  auto stB = [&](int slot, int half, int t) {
    unsigned short* dst = &lds[slot * 32768 + 16384 + half * 8192 + wave * 1024];
    const unsigned short* g = Bsrc + (size_t)(half * 128) * IN_F + t * BK;
    __builtin_amdgcn_global_load_lds((const GLOBAL_AS void*)g,
                                     (LDS_AS void*)dst, 16, 0, 0);
    __builtin_amdgcn_global_load_lds((const GLOBAL_AS void*)(g + (size_t)8 * IN_F),
                                     (LDS_AS void*)(dst + 512), 16, 0, 0);
  };

  auto rdA = [&](const unsigned short* Ar, int q, bf16x8 (&av)[2][2]) {
#pragma unroll
    for (int f = 0; f < 2; ++f) {
      const unsigned short* p = Ar + (wm * 128 + q * 32 + f * 16) * 64;
      av[f][0] = *reinterpret_cast<const bf16x8*>(p + rdoff0);
      av[f][1] = *reinterpret_cast<const bf16x8*>(p + rdoff1);
    }
  };
  auto rdB = [&](const unsigned short* Br) {
#pragma unroll
    for (int n = 0; n < 4; ++n) {
      const unsigned short* p = Br + (wn * 64 + n * 16) * 64;
      bv[n][0] = *reinterpret_cast<const bf16x8*>(p + rdoff0);
      bv[n][1] = *reinterpret_cast<const bf16x8*>(p + rdoff1);
    }
  };
  auto mfma16 = [&](bf16x8 (&av)[2][2], f32x4* r0, f32x4* r1) {
    __builtin_amdgcn_s_setprio(1);
#pragma unroll
    for (int kk = 0; kk < 2; ++kk) {
#pragma unroll
      for (int n = 0; n < 4; ++n) {
        r0[n] = __builtin_amdgcn_mfma_f32_16x16x32_bf16(av[0][kk], bv[n][kk], r0[n], 0, 0, 0);
        r1[n] = __builtin_amdgcn_mfma_f32_16x16x32_bf16(av[1][kk], bv[n][kk], r1[n], 0, 0, 0);
      }
    }
    __builtin_amdgcn_s_setprio(0);
  };

  const unsigned short* As0 = &lds[0];
  const unsigned short* Bs0 = &lds[16384];
  const unsigned short* As1 = &lds[32768];
  const unsigned short* Bs1 = &lds[49152];

  // prologue: tile0 {A0,A1,B0,B1} + tile1 {B0,B1} = 12 loads; keep tile1.B in flight
  stA(0, 0, 0); stA(0, 1, 0); stB(0, 0, 0); stB(0, 1, 0);
  stB(1, 0, 1); stB(1, 1, 1);
  VMCNT(4);
  BARRIER();

  for (int t = 0; t < NT; t += 2) {
    bf16x8 av[2][2];

    // ---- ph0: tile t, quadrant 0 (+ B-frag load); stage (t+1).A ----
    rdB(Bs0); rdA(As0, 0, av);
    stA(1, 0, t + 1); stA(1, 1, t + 1);
    BARRIER();
    mfma16(av, acc[0], acc[1]);
    BARRIER();

    // ---- ph1: q1; stage (t+2).B0 ----
    rdA(As0, 1, av);
    if (t + 2 < NT) stB(0, 0, t + 2);
    BARRIER();
    mfma16(av, acc[2], acc[3]);
    BARRIER();

    // ---- ph2: q2; stage (t+2).B1 ----
    rdA(As0, 2, av);
    if (t + 2 < NT) stB(0, 1, t + 2);
    BARRIER();
    mfma16(av, acc[4], acc[5]);
    BARRIER();

    // ---- ph3: q3; tile-boundary wait: (t+1) fully landed ----
    rdA(As0, 3, av);
    BARRIER();
    mfma16(av, acc[6], acc[7]);
    if (t + 2 < NT) { VMCNT(4); } else { VMCNT(0); }
    BARRIER();

    // ---- ph4: tile t+1, q0 (+ B-frags); stage (t+2).A0 ----
    rdB(Bs1); rdA(As1, 0, av);
    if (t + 2 < NT) stA(0, 0, t + 2);
    BARRIER();
    mfma16(av, acc[0], acc[1]);
    BARRIER();

    // ---- ph5: q1; stage (t+2).A1 ----
    rdA(As1, 1, av);
    if (t + 2 < NT) stA(0, 1, t + 2);
    BARRIER();
    mfma16(av, acc[2], acc[3]);
    BARRIER();

    // ---- ph6: q2; stage (t+3).B0 ----
    rdA(As1, 2, av);
    if (t + 3 < NT) stB(1, 0, t + 3);
    BARRIER();
    mfma16(av, acc[4], acc[5]);
    BARRIER();

    // ---- ph7: q3; stage (t+3).B1; boundary wait: (t+2) landed ----
    rdA(As1, 3, av);
    if (t + 3 < NT) stB(1, 1, t + 3);
    BARRIER();
    mfma16(av, acc[6], acc[7]);
    if (t + 3 < NT) { VMCNT(4); } else { VMCNT(0); }
    BARRIER();
  }

  // epilogue: C/D layout col=lane&15, row=(lane>>4)*4+reg
  const int colg0 = bn * BN + wn * 64 + lane15;
  const int rowg0 = bm * BM + wm * 128 + (lane >> 4) * 4;
#pragma unroll
  for (int ni = 0; ni < 4; ++ni) {
    const int colg = colg0 + ni * 16;
    const float bvs = bias[colg];
#pragma unroll
    for (int mi = 0; mi < 8; ++mi) {
      const int rowg = rowg0 + mi * 16;
#pragma unroll
      for (int r = 0; r < 4; ++r)
        C[(size_t)(rowg + r) * OUT_F + colg] = acc[mi][ni][r] + bvs;
    }
  }
}

// ---------------- fallback (only if ws too small) ----------------

__global__ void fallback_kernel(const float* __restrict__ x,
                                const float* __restrict__ wmu,
                                const float* __restrict__ wrho,
                                const float* __restrict__ weps,
                                const float* __restrict__ bmu,
                                const float* __restrict__ brho,
                                const float* __restrict__ beps,
                                float* __restrict__ out) {
  int o = blockIdx.x * blockDim.x + threadIdx.x;
  int t = blockIdx.y;
  float s = 0.f;
  const float* xr = x + (size_t)t * IN_F;
  const float* wm = wmu + (size_t)o * IN_F;
  const float* wr = wrho + (size_t)o * IN_F;
  const float* we = weps + (size_t)o * IN_F;
  for (int k = 0; k < IN_F; ++k)
    s += xr[k] * fmaf(softplus_f(wr[k]), we[k], wm[k]);
  out[(size_t)t * OUT_F + o] = s + fmaf(softplus_f(brho[o]), beps[o], bmu[o]);
}

// ---------------- launch ----------------

extern "C" void kernel_launch(void* const* d_in, const int* in_sizes, int n_in,
                              void* d_out, int out_size, void* d_ws, size_t ws_size,
                              hipStream_t stream) {
  const float* x    = (const float*)d_in[0];
  const float* wmu  = (const float*)d_in[1];
  const float* wrho = (const float*)d_in[2];
  const float* bmu  = (const float*)d_in[3];
  const float* brho = (const float*)d_in[4];
  const float* weps = (const float*)d_in[5];
  const float* beps = (const float*)d_in[6];
  float* out = (float*)d_out;

  const size_t xb_off   = 0;
  const size_t wb_off   = (size_t)TOKENS * IN_F * 2;            // 64 MB
  const size_t bias_off = wb_off + (size_t)OUT_F * IN_F * 2;    // +32 MB
  const size_t needed   = bias_off + (size_t)OUT_F * 4;

  if (ws_size < needed) {
    dim3 g(OUT_F / 256, TOKENS);
    hipLaunchKernelGGL(fallback_kernel, g, dim3(256), 0, stream,
                       x, wmu, wrho, weps, bmu, brho, beps, out);
    return;
  }

  unsigned short* xb = (unsigned short*)((char*)d_ws + xb_off);
  unsigned short* wb = (unsigned short*)((char*)d_ws + wb_off);
  float* bias = (float*)((char*)d_ws + bias_off);

  hipLaunchKernelGGL(convert_x_kernel, dim3(2048), dim3(256), 0, stream,
                     x, xb, (long long)TOKENS * IN_F / 4);
  hipLaunchKernelGGL(sample_weight_kernel, dim3(2048), dim3(256), 0, stream,
                     wmu, wrho, weps, wb, (long long)OUT_F * IN_F / 4);
  hipLaunchKernelGGL(bias_kernel, dim3(16), dim3(256), 0, stream,
                     bmu, brho, beps, bias);

  hipLaunchKernelGGL(gemm_bt_kernel,
                     dim3((TOKENS / BM) * (OUT_F / BN)), dim3(THREADS), 0, stream,
                     xb, wb, bias, out);
}

// Round 4
// 316.431 us; speedup vs baseline: 1.5766x; 1.0451x over previous
//
#include <hip/hip_runtime.h>
#include <hip/hip_bf16.h>
#include <cstdint>

#define TOKENS 8192
#define IN_F   4096
#define OUT_F  4096

#define BM 256
#define BN 256
#define BK 64
#define NT (IN_F / BK)   // 64 K-tiles
#define THREADS 512

typedef __attribute__((ext_vector_type(8))) short bf16x8;
typedef __attribute__((ext_vector_type(4))) float f32x4;

#define GLOBAL_AS __attribute__((address_space(1)))
#define LDS_AS    __attribute__((address_space(3)))

#define BARRIER() do { __builtin_amdgcn_s_barrier(); asm volatile("" ::: "memory"); } while (0)
#define VMCNT(n)  do { asm volatile("s_waitcnt vmcnt(" #n ")" ::: "memory"); } while (0)

__device__ __forceinline__ unsigned short f2bf(float f) {
  union { float f; unsigned int u; } v;
  v.f = f;
  unsigned int r = 0x7FFFu + ((v.u >> 16) & 1u);
  return (unsigned short)((v.u + r) >> 16);
}

__device__ __forceinline__ float softplus_f(float x) {
  return log1pf(expf(x));
}

// ---------------- fused prep kernel ----------------
// range [0, NW4): sample W -> bf16; [NW4, NW4+NX4): convert x -> bf16;
// [NW4+NX4, +NB4): bias.

#define NW4 ((long long)OUT_F * IN_F / 4)
#define NX4 ((long long)TOKENS * IN_F / 4)
#define NB4 (OUT_F / 4)

__global__ void prep_kernel(const float* __restrict__ x,
                            const float* __restrict__ wmu,
                            const float* __restrict__ wrho,
                            const float* __restrict__ weps,
                            const float* __restrict__ bmu,
                            const float* __restrict__ brho,
                            const float* __restrict__ beps,
                            unsigned short* __restrict__ xb,
                            unsigned short* __restrict__ wb,
                            float* __restrict__ bias) {
  long long i = (long long)blockIdx.x * blockDim.x + threadIdx.x;
  long long stride = (long long)gridDim.x * blockDim.x;
  const long long total = NW4 + NX4 + NB4;
  for (; i < total; i += stride) {
    if (i < NW4) {
      float4 m = reinterpret_cast<const float4*>(wmu)[i];
      float4 r = reinterpret_cast<const float4*>(wrho)[i];
      float4 e = reinterpret_cast<const float4*>(weps)[i];
      ushort4 o;
      o.x = f2bf(fmaf(softplus_f(r.x), e.x, m.x));
      o.y = f2bf(fmaf(softplus_f(r.y), e.y, m.y));
      o.z = f2bf(fmaf(softplus_f(r.z), e.z, m.z));
      o.w = f2bf(fmaf(softplus_f(r.w), e.w, m.w));
      reinterpret_cast<ushort4*>(wb)[i] = o;
    } else if (i < NW4 + NX4) {
      long long j = i - NW4;
      float4 m = reinterpret_cast<const float4*>(x)[j];
      ushort4 o;
      o.x = f2bf(m.x); o.y = f2bf(m.y); o.z = f2bf(m.z); o.w = f2bf(m.w);
      reinterpret_cast<ushort4*>(xb)[j] = o;
    } else {
      long long j = i - NW4 - NX4;
      float4 m = reinterpret_cast<const float4*>(bmu)[j];
      float4 r = reinterpret_cast<const float4*>(brho)[j];
      float4 e = reinterpret_cast<const float4*>(beps)[j];
      float4 o;
      o.x = fmaf(softplus_f(r.x), e.x, m.x);
      o.y = fmaf(softplus_f(r.y), e.y, m.y);
      o.z = fmaf(softplus_f(r.z), e.z, m.z);
      o.w = fmaf(softplus_f(r.w), e.w, m.w);
      reinterpret_cast<float4*>(bias)[j] = o;
    }
  }
}

// ---------------- GEMM: 256x256 8-phase, 3-slot A ring + 2-slot B ring ----------------
// LDS 160 KiB: A slots 0..2 (32 KiB each), B slots 0..1 (32 KiB each).
// 8 waves (2M x 4N), per-wave out 128x64. Per K-tile: 4 phases x 16 MFMA;
// B-frags read once (ph0) into regs. Staging of tile t+2 spread flat over
// ph1..ph3; every stage waits >= 5 phases after issue (vmcnt(8) boundary).
// Slot liveness: B slot (t+2)&1 == t&1 is dead after ph0's trailing barrier
// (B lives in regs); A slot (t+2)%3 was last read in tile t-1.
// LDS swizzle: chunk ^= (row & 7) via pre-swizzled global source (linear
// global_load_lds dest) + matching XOR on ds_read (rule 21 involution).

__global__ __launch_bounds__(THREADS, 2) void gemm_bt_kernel(
    const unsigned short* __restrict__ A,   // [TOKENS][IN_F] bf16
    const unsigned short* __restrict__ B,   // [OUT_F][IN_F] bf16
    const float* __restrict__ bias,         // [OUT_F]
    float* __restrict__ C)                  // [TOKENS][OUT_F]
{
  __shared__ unsigned short lds[5 * 16384]; // 160 KiB

  const int tid  = threadIdx.x;
  const int lane = tid & 63;
  const int wave = tid >> 6;   // 0..7
  const int wm   = wave >> 2;  // 0..1
  const int wn   = wave & 3;   // 0..3

  // XCD-aware bijective block swizzle (512 = 8 XCD chunks x 64)
  const int bid = blockIdx.x;
  const int wg  = (bid & 7) * 64 + (bid >> 3);
  const int ch  = wg >> 6;
  const int idx = wg & 63;
  const int bm  = (ch >> 1) * 8 + (idx >> 3);  // 0..31
  const int bn  = (ch & 1) * 8 + (idx & 7);    // 0..15

  const int lane15 = lane & 15;
  const int cgrp   = lane >> 4;                // 0..3
  const int rdoff0 = lane15 * 64 + ((cgrp ^ (lane & 7)) * 8);
  const int rdoff1 = lane15 * 64 + (((4 + cgrp) ^ (lane & 7)) * 8);

  // staging: per-lane pre-swizzled global source
  const int srow = lane >> 3;                  // 0..7
  const int scol = ((lane & 7) ^ srow) * 8;    // swizzled 16B chunk -> elems
  const unsigned short* Asrc = A + (size_t)(bm * BM + wave * 16 + srow) * IN_F + scol;
  const unsigned short* Bsrc = B + (size_t)(bn * BN + wave * 16 + srow) * IN_F + scol;

  f32x4 acc[8][4] = {};
  bf16x8 bv[4][2];

  auto stA = [&](int slot, int half, int t) {
    unsigned short* dst = &lds[slot * 16384 + half * 8192 + wave * 1024];
    const unsigned short* g = Asrc + (size_t)(half * 128) * IN_F + t * BK;
    __builtin_amdgcn_global_load_lds((const GLOBAL_AS void*)g,
                                     (LDS_AS void*)dst, 16, 0, 0);
    __builtin_amdgcn_global_load_lds((const GLOBAL_AS void*)(g + (size_t)8 * IN_F),
                                     (LDS_AS void*)(dst + 512), 16, 0, 0);
  };
  auto stB = [&](int slot, int half, int t) {
    unsigned short* dst = &lds[49152 + slot * 16384 + half * 8192 + wave * 1024];
    const unsigned short* g = Bsrc + (size_t)(half * 128) * IN_F + t * BK;
    __builtin_amdgcn_global_load_lds((const GLOBAL_AS void*)g,
                                     (LDS_AS void*)dst, 16, 0, 0);
    __builtin_amdgcn_global_load_lds((const GLOBAL_AS void*)(g + (size_t)8 * IN_F),
                                     (LDS_AS void*)(dst + 512), 16, 0, 0);
  };

  auto rdA = [&](const unsigned short* Ar, int q, bf16x8 (&av)[2][2]) {
#pragma unroll
    for (int f = 0; f < 2; ++f) {
      const unsigned short* p = Ar + (wm * 128 + q * 32 + f * 16) * 64;
      av[f][0] = *reinterpret_cast<const bf16x8*>(p + rdoff0);
      av[f][1] = *reinterpret_cast<const bf16x8*>(p + rdoff1);
    }
  };
  auto rdB = [&](const unsigned short* Br) {
#pragma unroll
    for (int n = 0; n < 4; ++n) {
      const unsigned short* p = Br + (wn * 64 + n * 16) * 64;
      bv[n][0] = *reinterpret_cast<const bf16x8*>(p + rdoff0);
      bv[n][1] = *reinterpret_cast<const bf16x8*>(p + rdoff1);
    }
  };
  auto mfma16 = [&](bf16x8 (&av)[2][2], f32x4* r0, f32x4* r1) {
    __builtin_amdgcn_s_setprio(1);
#pragma unroll
    for (int kk = 0; kk < 2; ++kk) {
#pragma unroll
      for (int n = 0; n < 4; ++n) {
        r0[n] = __builtin_amdgcn_mfma_f32_16x16x32_bf16(av[0][kk], bv[n][kk], r0[n], 0, 0, 0);
        r1[n] = __builtin_amdgcn_mfma_f32_16x16x32_bf16(av[1][kk], bv[n][kk], r1[n], 0, 0, 0);
      }
    }
    __builtin_amdgcn_s_setprio(0);
  };

  // prologue: stage t0 fully, then t1 fully; drain t0 only
  stA(0, 0, 0); stA(0, 1, 0); stB(0, 0, 0); stB(0, 1, 0);
  stA(1, 0, 1); stA(1, 1, 1); stB(1, 0, 1); stB(1, 1, 1);
  VMCNT(8);
  BARRIER();

  int aslot = 0, bslot = 0;
  for (int t = 0; t < NT; ++t) {
    const unsigned short* As = &lds[aslot * 16384];
    const unsigned short* Bs = &lds[49152 + bslot * 16384];
    int a2 = aslot + 2; if (a2 >= 3) a2 -= 3;   // A slot for tile t+2
    const bool pf = (t + 2 < NT);
    bf16x8 av[2][2];

    // ---- ph0: B-frags + A q0 (12 ds_reads); no staging ----
    rdB(Bs); rdA(As, 0, av);
    BARRIER();
    mfma16(av, acc[0], acc[1]);
    BARRIER();

    // ---- ph1: A q1; stage (t+2).A0 ----
    rdA(As, 1, av);
    if (pf) stA(a2, 0, t + 2);
    BARRIER();
    mfma16(av, acc[2], acc[3]);
    BARRIER();

    // ---- ph2: A q2; stage (t+2).A1 + (t+2).B0 ----
    rdA(As, 2, av);
    if (pf) { stA(a2, 1, t + 2); stB(bslot, 0, t + 2); }
    BARRIER();
    mfma16(av, acc[4], acc[5]);
    BARRIER();

    // ---- ph3: A q3; stage (t+2).B1; boundary wait ----
    rdA(As, 3, av);
    if (pf) stB(bslot, 1, t + 2);
    BARRIER();
    mfma16(av, acc[6], acc[7]);
    if (pf)                { VMCNT(8); BARRIER(); }  // t+1 landed; t+2 in flight
    else if (t + 1 < NT)   { VMCNT(0); BARRIER(); }  // drain last prefetch
    // t == NT-1: no further LDS reads; fall through to epilogue

    aslot = (aslot == 2) ? 0 : aslot + 1;
    bslot ^= 1;
  }

  // epilogue: C/D layout col=lane&15, row=(lane>>4)*4+reg
  const int colg0 = bn * BN + wn * 64 + lane15;
  const int rowg0 = bm * BM + wm * 128 + (lane >> 4) * 4;
#pragma unroll
  for (int ni = 0; ni < 4; ++ni) {
    const int colg = colg0 + ni * 16;
    const float bvs = bias[colg];
#pragma unroll
    for (int mi = 0; mi < 8; ++mi) {
      const int rowg = rowg0 + mi * 16;
#pragma unroll
      for (int r = 0; r < 4; ++r)
        C[(size_t)(rowg + r) * OUT_F + colg] = acc[mi][ni][r] + bvs;
    }
  }
}

// ---------------- fallback (only if ws too small) ----------------

__global__ void fallback_kernel(const float* __restrict__ x,
                                const float* __restrict__ wmu,
                                const float* __restrict__ wrho,
                                const float* __restrict__ weps,
                                const float* __restrict__ bmu,
                                const float* __restrict__ brho,
                                const float* __restrict__ beps,
                                float* __restrict__ out) {
  int o = blockIdx.x * blockDim.x + threadIdx.x;
  int t = blockIdx.y;
  float s = 0.f;
  const float* xr = x + (size_t)t * IN_F;
  const float* wm = wmu + (size_t)o * IN_F;
  const float* wr = wrho + (size_t)o * IN_F;
  const float* we = weps + (size_t)o * IN_F;
  for (int k = 0; k < IN_F; ++k)
    s += xr[k] * fmaf(softplus_f(wr[k]), we[k], wm[k]);
  out[(size_t)t * OUT_F + o] = s + fmaf(softplus_f(brho[o]), beps[o], bmu[o]);
}

// ---------------- launch ----------------

extern "C" void kernel_launch(void* const* d_in, const int* in_sizes, int n_in,
                              void* d_out, int out_size, void* d_ws, size_t ws_size,
                              hipStream_t stream) {
  const float* x    = (const float*)d_in[0];
  const float* wmu  = (const float*)d_in[1];
  const float* wrho = (const float*)d_in[2];
  const float* bmu  = (const float*)d_in[3];
  const float* brho = (const float*)d_in[4];
  const float* weps = (const float*)d_in[5];
  const float* beps = (const float*)d_in[6];
  float* out = (float*)d_out;

  const size_t xb_off   = 0;
  const size_t wb_off   = (size_t)TOKENS * IN_F * 2;            // 64 MB
  const size_t bias_off = wb_off + (size_t)OUT_F * IN_F * 2;    // +32 MB
  const size_t needed   = bias_off + (size_t)OUT_F * 4;

  if (ws_size < needed) {
    dim3 g(OUT_F / 256, TOKENS);
    hipLaunchKernelGGL(fallback_kernel, g, dim3(256), 0, stream,
                       x, wmu, wrho, weps, bmu, brho, beps, out);
    return;
  }

  unsigned short* xb = (unsigned short*)((char*)d_ws + xb_off);
  unsigned short* wb = (unsigned short*)((char*)d_ws + wb_off);
  float* bias = (float*)((char*)d_ws + bias_off);

  hipLaunchKernelGGL(prep_kernel, dim3(2048), dim3(256), 0, stream,
                     x, wmu, wrho, weps, bmu, brho, beps, xb, wb, bias);

  hipLaunchKernelGGL(gemm_bt_kernel,
                     dim3((TOKENS / BM) * (OUT_F / BN)), dim3(THREADS), 0, stream,
                     xb, wb, bias, out);
}